// Round 5
// baseline (238.160 us; speedup 1.0000x reference)
//
#include <hip/hip_runtime.h>

#define POOL 7
#define IMG_W 256
#define IMG_C 512
#define NUM_ROIS 1024
#define CCHUNK 64                    // channels per chunk (one XCD's slice)
#define NCHUNK (IMG_C / CCHUNK)      // 8 chunks == 8 XCDs

typedef float f4 __attribute__((ext_vector_type(4)));

// ---------------- kernel 1: spatial counting-sort of ROI indices ----------
// Key = 32x32-px tile of (x1,y1). One block, 1024 threads. Within-bucket
// order nondeterministic — harmless (each roi written exactly once).
__global__ __launch_bounds__(1024) void sort_rois_kernel(
    const int* __restrict__ rois, int* __restrict__ order)
{
    __shared__ int hist[64];
    __shared__ int base[64];
    const int tid = threadIdx.x;

    if (tid < 64) hist[tid] = 0;
    __syncthreads();

    const int x1 = rois[4 * tid + 0];
    const int y1 = rois[4 * tid + 1];
    const int key = ((y1 >> 5) << 3) | (x1 >> 5);
    const int rank = atomicAdd(&hist[key], 1);
    __syncthreads();

    if (tid == 0) {
        int run = 0;
#pragma unroll
        for (int k = 0; k < 64; ++k) { base[k] = run; run += hist[k]; }
    }
    __syncthreads();

    order[base[key] + rank] = tid;
}

// ---------------- kernel 2: channel-sliced ROI pooling --------------------
// Block = (sorted-roi, py, chunk); chunk = bid&7 -> XCD partition. Each XCD
// only touches a 64-channel slice of the image (16.75 MB), so its sorted
// sliding reuse window (~2.3 MB) fits the 4 MB per-XCD L2: inter-ROI
// redundant reads become L2 hits (low latency) instead of IF$/HBM traffic.
// 128 threads: 16-lane group s (0..7) = px (s==7 idle), lane-in-group = f4
// channel group. Per-group 256 B segments = 4 full cache lines.
__global__ __launch_bounds__(128) void roi_pool_kernel(
    const float* __restrict__ img,
    const int*   __restrict__ rois,
    const int*   __restrict__ order,
    float*       __restrict__ out)
{
    const int bid   = blockIdx.x;          // 0 .. 1024*7*8-1
    const int chunk = bid & 7;             // channel slice -> XCD
    const int slot  = bid >> 3;            // 0..7167 = (sorted-roi, py)
    const int sidx  = slot / POOL;
    const int py    = slot - sidx * POOL;
    const int roi   = order[sidx];

    const int4 rb = ((const int4*)rois)[roi];
    const int x1 = __builtin_amdgcn_readfirstlane(rb.x);
    const int y1 = __builtin_amdgcn_readfirstlane(rb.y);
    const int x2 = __builtin_amdgcn_readfirstlane(rb.z);
    const int y2 = __builtin_amdgcn_readfirstlane(rb.w);

    const float h = (float)(y2 - y1);
    const float w = (float)(x2 - x1);
    const float sy = h / (float)POOL;      // reference numerics: h/P, py*(h/P)
    const float sx = w / (float)POOL;

    const float ys = (float)py * sy;
    const int   y0 = (int)floorf(ys);
    const int   y1i = min(y0 + 1, max(y2 - y1 - 1, 0));
    const float wy = ys - (float)y0;

    const size_t rowstride = (size_t)IMG_W * IMG_C;
    const size_t choff = (size_t)chunk * CCHUNK;
    const float* row0 = img + (size_t)(y1 + y0)  * rowstride + choff;
    const float* row1 = img + (size_t)(y1 + y1i) * rowstride + choff;

    const int t  = threadIdx.x;            // 0..127
    const int s  = t >> 4;                 // px slot 0..7 (7 idle)
    const int cg = t & 15;                 // f4 group within 64-ch chunk

    if (s < POOL) {
        const int cmax = max(x2 - x1 - 1, 0);
        const float xs = (float)s * sx;
        const int   x0 = (int)floorf(xs);
        const int   x1i = min(x0 + 1, cmax);
        const float wx = xs - (float)x0;
        const int c0 = x1 + x0, c1 = x1 + x1i;

        const f4 v00 = ((const f4*)(row0 + (size_t)c0 * IMG_C))[cg];
        const f4 v01 = ((const f4*)(row0 + (size_t)c1 * IMG_C))[cg];
        const f4 v10 = ((const f4*)(row1 + (size_t)c0 * IMG_C))[cg];
        const f4 v11 = ((const f4*)(row1 + (size_t)c1 * IMG_C))[cg];

        const float w00 = (1.0f - wy) * (1.0f - wx);
        const float w01 = (1.0f - wy) * wx;
        const float w10 = wy * (1.0f - wx);
        const float w11 = wy * wx;

        f4 o = v00 * w00 + v01 * w01 + v10 * w10 + v11 * w11;

        f4* po = (f4*)(out + (((size_t)roi * (POOL * POOL) + (size_t)py * POOL + s) * IMG_C) + choff);
        __builtin_nontemporal_store(o, po + cg);
    }
}

extern "C" void kernel_launch(void* const* d_in, const int* in_sizes, int n_in,
                              void* d_out, int out_size, void* d_ws, size_t ws_size,
                              hipStream_t stream) {
    const float* img  = (const float*)d_in[0];
    const int*   rois = (const int*)d_in[1];
    float* out = (float*)d_out;
    int* order = (int*)d_ws;               // 1024 ints, rewritten every call

    sort_rois_kernel<<<1, 1024, 0, stream>>>(rois, order);
    roi_pool_kernel<<<NUM_ROIS * POOL * NCHUNK, 128, 0, stream>>>(img, rois, order, out);
}